// Round 1
// baseline (890.323 us; speedup 1.0000x reference)
//
#include <hip/hip_runtime.h>
#include <math.h>

// Problem constants (from reference)
#define B_  4096
#define T_  193
#define D_  50
#define H_  50
#define G_  200   // 4*H
#define V_  11
#define R_  4     // batch rows per block
#define LSTRIDE 52  // padded row stride in LDS (float4-aligned: 52 % 4 == 0)

__device__ __forceinline__ float sigmoidf_(float v) {
    return 1.0f / (1.0f + __expf(-v));
}
__device__ __forceinline__ float tanhf_(float v) {
    // tanh(x) = 2*sigmoid(2x) - 1 ; saturates correctly at +-inf
    return 2.0f / (1.0f + __expf(-2.0f * v)) - 1.0f;
}

__global__ __launch_bounds__(256) void lstm_fused_kernel(
    const float* __restrict__ x,      // [B, T, D]
    const float* __restrict__ W_ih,   // [4H, D]
    const float* __restrict__ W_hh,   // [4H, H]
    const float* __restrict__ b_ih,   // [4H]
    const float* __restrict__ b_hh,   // [4H]
    const float* __restrict__ fc_w,   // [V, H]
    const float* __restrict__ fc_b,   // [V]
    float* __restrict__ out)          // [B, V]
{
    __shared__ float x_lds[2][R_ * LSTRIDE];
    __shared__ float h_lds[R_ * LSTRIDE];
    __shared__ float gates_lds[R_][G_];
    __shared__ float logits_lds[R_][V_];

    const int tid  = threadIdx.x;
    const int row0 = blockIdx.x * R_;
    const int r_   = tid / H_;   // (r_, j_) valid for tid < 200
    const int j_   = tid % H_;

    // ---- per-thread register-resident weight rows (tid < 200) ----
    float w_ih[D_];
    float w_hh[H_];
    float bsum = 0.0f;
    if (tid < G_) {
        const float* wi = &W_ih[tid * D_];
        const float* wh = &W_hh[tid * H_];
        #pragma unroll
        for (int k = 0; k < D_; ++k) w_ih[k] = wi[k];
        #pragma unroll
        for (int k = 0; k < H_; ++k) w_hh[k] = wh[k];
        bsum = b_ih[tid] + b_hh[tid];
    }

    // init h = 0
    if (tid < R_ * LSTRIDE) h_lds[tid] = 0.0f;
    // load x_t for t = 0
    if (tid < G_) {
        x_lds[0][r_ * LSTRIDE + j_] = x[(size_t)(row0 + r_) * T_ * D_ + j_];
    }
    float c_reg = 0.0f;  // cell state for (r_, j_), tid < 200
    __syncthreads();

    int buf = 0;
    for (int t = 0; t < T_; ++t) {
        // prefetch next timestep's x into a register
        float xn = 0.0f;
        if (tid < G_ && (t + 1) < T_) {
            xn = x[(size_t)(row0 + r_) * T_ * D_ + (size_t)(t + 1) * D_ + j_];
        }

        if (tid < G_) {
            // gate pre-activation for gate-row `tid`, for R_ batch rows
            float accx[R_], acch[R_];
            #pragma unroll
            for (int r = 0; r < R_; ++r) { accx[r] = 0.0f; acch[r] = 0.0f; }

            #pragma unroll
            for (int kc = 0; kc < 12; ++kc) {          // 48 of 50 k's
                #pragma unroll
                for (int r = 0; r < R_; ++r) {
                    const float4 xv = *reinterpret_cast<const float4*>(
                        &x_lds[buf][r * LSTRIDE + kc * 4]);
                    const float4 hv = *reinterpret_cast<const float4*>(
                        &h_lds[r * LSTRIDE + kc * 4]);
                    accx[r] = fmaf(w_ih[kc * 4 + 0], xv.x, accx[r]);
                    accx[r] = fmaf(w_ih[kc * 4 + 1], xv.y, accx[r]);
                    accx[r] = fmaf(w_ih[kc * 4 + 2], xv.z, accx[r]);
                    accx[r] = fmaf(w_ih[kc * 4 + 3], xv.w, accx[r]);
                    acch[r] = fmaf(w_hh[kc * 4 + 0], hv.x, acch[r]);
                    acch[r] = fmaf(w_hh[kc * 4 + 1], hv.y, acch[r]);
                    acch[r] = fmaf(w_hh[kc * 4 + 2], hv.z, acch[r]);
                    acch[r] = fmaf(w_hh[kc * 4 + 3], hv.w, acch[r]);
                }
            }
            // remainder k = 48, 49
            #pragma unroll
            for (int r = 0; r < R_; ++r) {
                const float2 xv = *reinterpret_cast<const float2*>(
                    &x_lds[buf][r * LSTRIDE + 48]);
                const float2 hv = *reinterpret_cast<const float2*>(
                    &h_lds[r * LSTRIDE + 48]);
                accx[r] = fmaf(w_ih[48], xv.x, accx[r]);
                accx[r] = fmaf(w_ih[49], xv.y, accx[r]);
                acch[r] = fmaf(w_hh[48], hv.x, acch[r]);
                acch[r] = fmaf(w_hh[49], hv.y, acch[r]);
            }
            #pragma unroll
            for (int r = 0; r < R_; ++r) {
                gates_lds[r][tid] = bsum + accx[r] + acch[r];
            }
        }
        __syncthreads();

        if (tid < G_) {
            // stash the prefetched x into the other buffer
            x_lds[buf ^ 1][r_ * LSTRIDE + j_] = xn;

            // LSTM cell update for (r_, j_)  [gate order: i, f, g, o]
            const float gi = gates_lds[r_][j_];
            const float gf = gates_lds[r_][H_ + j_];
            const float gg = gates_lds[r_][2 * H_ + j_];
            const float go = gates_lds[r_][3 * H_ + j_];
            const float ig = sigmoidf_(gi);
            const float fg = sigmoidf_(gf);
            const float gg2 = tanhf_(gg);
            const float og = sigmoidf_(go);
            c_reg = fg * c_reg + ig * gg2;
            h_lds[r_ * LSTRIDE + j_] = og * tanhf_(c_reg);
        }
        __syncthreads();
        buf ^= 1;
    }

    // ---- FC head: logits[r][v] = fc_b[v] + sum_j relu(h[r][j]) * fc_w[v][j] ----
    if (tid < R_ * V_) {
        const int r = tid / V_;
        const int v = tid % V_;
        float acc = fc_b[v];
        const float* fw = &fc_w[v * H_];
        #pragma unroll
        for (int j = 0; j < H_; ++j) {
            float hj = h_lds[r * LSTRIDE + j];
            hj = hj > 0.0f ? hj : 0.0f;
            acc = fmaf(hj, fw[j], acc);
        }
        logits_lds[r][v] = acc;
    }
    __syncthreads();

    // ---- log_softmax over V = 11 ----
    if (tid < R_ * V_) {
        const int r = tid / V_;
        const int v = tid % V_;
        float m = -1e30f;
        #pragma unroll
        for (int u = 0; u < V_; ++u) m = fmaxf(m, logits_lds[r][u]);
        float s = 0.0f;
        #pragma unroll
        for (int u = 0; u < V_; ++u) s += __expf(logits_lds[r][u] - m);
        out[(size_t)(row0 + r) * V_ + v] = logits_lds[r][v] - m - __logf(s);
    }
}

extern "C" void kernel_launch(void* const* d_in, const int* in_sizes, int n_in,
                              void* d_out, int out_size, void* d_ws, size_t ws_size,
                              hipStream_t stream) {
    const float* x    = (const float*)d_in[0];
    const float* W_ih = (const float*)d_in[1];
    const float* W_hh = (const float*)d_in[2];
    const float* b_ih = (const float*)d_in[3];
    const float* b_hh = (const float*)d_in[4];
    const float* fc_w = (const float*)d_in[5];
    const float* fc_b = (const float*)d_in[6];
    float* out = (float*)d_out;

    const int blocks = B_ / R_;  // 1024
    lstm_fused_kernel<<<blocks, 256, 0, stream>>>(
        x, W_ih, W_hh, b_ih, b_hh, fc_w, fc_b, out);
}

// Round 2
// 871.935 us; speedup vs baseline: 1.0211x; 1.0211x over previous
//
#include <hip/hip_runtime.h>
#include <math.h>

// Problem constants (from reference)
#define B_  4096
#define T_  193
#define D_  50
#define H_  50
#define G_  200   // 4*H
#define V_  11
#define R_  4     // batch rows per block
#define LSTRIDE 52  // padded row stride in LDS (float4-aligned: 52 % 4 == 0)

__device__ __forceinline__ float sigmoidf_(float v) {
    return 1.0f / (1.0f + __expf(-v));
}
__device__ __forceinline__ float tanhf_(float v) {
    // tanh(x) = 2*sigmoid(2x) - 1 ; saturates correctly at +-inf
    return 2.0f / (1.0f + __expf(-2.0f * v)) - 1.0f;
}

// __launch_bounds__(256, 2): min 2 waves/EU -> VGPR cap 256. The weight rows
// (w_ih[50] + w_hh[50]) + accumulators need ~140 VGPRs; without this the
// allocator capped at 80 and spilled the weights to scratch (R1: VGPR=80,
// VALUBusy 70%, 890us).
__global__ __launch_bounds__(256, 2) void lstm_fused_kernel(
    const float* __restrict__ x,      // [B, T, D]
    const float* __restrict__ W_ih,   // [4H, D]
    const float* __restrict__ W_hh,   // [4H, H]
    const float* __restrict__ b_ih,   // [4H]
    const float* __restrict__ b_hh,   // [4H]
    const float* __restrict__ fc_w,   // [V, H]
    const float* __restrict__ fc_b,   // [V]
    float* __restrict__ out)          // [B, V]
{
    __shared__ float x_lds[2][R_ * LSTRIDE];
    __shared__ float h_lds[R_ * LSTRIDE];
    __shared__ float gates_lds[R_][G_];
    __shared__ float logits_lds[R_][V_];

    const int tid  = threadIdx.x;
    const int row0 = blockIdx.x * R_;
    const int r_   = tid / H_;   // (r_, j_) valid for tid < 200
    const int j_   = tid % H_;

    // ---- per-thread register-resident weight rows (tid < 200) ----
    float w_ih[D_];
    float w_hh[H_];
    float bsum = 0.0f;
    if (tid < G_) {
        const float* wi = &W_ih[tid * D_];
        const float* wh = &W_hh[tid * H_];
        #pragma unroll
        for (int k = 0; k < D_; ++k) w_ih[k] = wi[k];
        #pragma unroll
        for (int k = 0; k < H_; ++k) w_hh[k] = wh[k];
        bsum = b_ih[tid] + b_hh[tid];
    }

    // init h = 0
    if (tid < R_ * LSTRIDE) h_lds[tid] = 0.0f;
    // load x_t for t = 0
    if (tid < G_) {
        x_lds[0][r_ * LSTRIDE + j_] = x[(size_t)(row0 + r_) * T_ * D_ + j_];
    }
    float c_reg = 0.0f;  // cell state for (r_, j_), tid < 200
    __syncthreads();

    int buf = 0;
    for (int t = 0; t < T_; ++t) {
        // prefetch next timestep's x into a register (hides under FMA phase)
        float xn = 0.0f;
        if (tid < G_ && (t + 1) < T_) {
            xn = x[(size_t)(row0 + r_) * T_ * D_ + (size_t)(t + 1) * D_ + j_];
        }

        if (tid < G_) {
            // gate pre-activation for gate-row `tid`, for R_ batch rows.
            // single merged accumulator per row (x and h terms interleave)
            float acc[R_];
            #pragma unroll
            for (int r = 0; r < R_; ++r) acc[r] = 0.0f;

            #pragma unroll
            for (int kc = 0; kc < 12; ++kc) {          // 48 of 50 k's
                #pragma unroll
                for (int r = 0; r < R_; ++r) {
                    const float4 xv = *reinterpret_cast<const float4*>(
                        &x_lds[buf][r * LSTRIDE + kc * 4]);
                    const float4 hv = *reinterpret_cast<const float4*>(
                        &h_lds[r * LSTRIDE + kc * 4]);
                    acc[r] = fmaf(w_ih[kc * 4 + 0], xv.x, acc[r]);
                    acc[r] = fmaf(w_ih[kc * 4 + 1], xv.y, acc[r]);
                    acc[r] = fmaf(w_ih[kc * 4 + 2], xv.z, acc[r]);
                    acc[r] = fmaf(w_ih[kc * 4 + 3], xv.w, acc[r]);
                    acc[r] = fmaf(w_hh[kc * 4 + 0], hv.x, acc[r]);
                    acc[r] = fmaf(w_hh[kc * 4 + 1], hv.y, acc[r]);
                    acc[r] = fmaf(w_hh[kc * 4 + 2], hv.z, acc[r]);
                    acc[r] = fmaf(w_hh[kc * 4 + 3], hv.w, acc[r]);
                }
            }
            // remainder k = 48, 49
            #pragma unroll
            for (int r = 0; r < R_; ++r) {
                const float2 xv = *reinterpret_cast<const float2*>(
                    &x_lds[buf][r * LSTRIDE + 48]);
                const float2 hv = *reinterpret_cast<const float2*>(
                    &h_lds[r * LSTRIDE + 48]);
                acc[r] = fmaf(w_ih[48], xv.x, acc[r]);
                acc[r] = fmaf(w_ih[49], xv.y, acc[r]);
                acc[r] = fmaf(w_hh[48], hv.x, acc[r]);
                acc[r] = fmaf(w_hh[49], hv.y, acc[r]);
            }
            #pragma unroll
            for (int r = 0; r < R_; ++r) {
                gates_lds[r][tid] = bsum + acc[r];
            }
        }
        __syncthreads();

        if (tid < G_) {
            // stash the prefetched x into the other buffer
            x_lds[buf ^ 1][r_ * LSTRIDE + j_] = xn;

            // LSTM cell update for (r_, j_)  [gate order: i, f, g, o]
            const float gi = gates_lds[r_][j_];
            const float gf = gates_lds[r_][H_ + j_];
            const float gg = gates_lds[r_][2 * H_ + j_];
            const float go = gates_lds[r_][3 * H_ + j_];
            const float ig = sigmoidf_(gi);
            const float fg = sigmoidf_(gf);
            const float gg2 = tanhf_(gg);
            const float og = sigmoidf_(go);
            c_reg = fg * c_reg + ig * gg2;
            h_lds[r_ * LSTRIDE + j_] = og * tanhf_(c_reg);
        }
        __syncthreads();
        buf ^= 1;
    }

    // ---- FC head: logits[r][v] = fc_b[v] + sum_j relu(h[r][j]) * fc_w[v][j] ----
    if (tid < R_ * V_) {
        const int r = tid / V_;
        const int v = tid % V_;
        float acc = fc_b[v];
        const float* fw = &fc_w[v * H_];
        #pragma unroll
        for (int j = 0; j < H_; ++j) {
            float hj = h_lds[r * LSTRIDE + j];
            hj = hj > 0.0f ? hj : 0.0f;
            acc = fmaf(hj, fw[j], acc);
        }
        logits_lds[r][v] = acc;
    }
    __syncthreads();

    // ---- log_softmax over V = 11 ----
    if (tid < R_ * V_) {
        const int r = tid / V_;
        const int v = tid % V_;
        float m = -1e30f;
        #pragma unroll
        for (int u = 0; u < V_; ++u) m = fmaxf(m, logits_lds[r][u]);
        float s = 0.0f;
        #pragma unroll
        for (int u = 0; u < V_; ++u) s += __expf(logits_lds[r][u] - m);
        out[(size_t)(row0 + r) * V_ + v] = logits_lds[r][v] - m - __logf(s);
    }
}

extern "C" void kernel_launch(void* const* d_in, const int* in_sizes, int n_in,
                              void* d_out, int out_size, void* d_ws, size_t ws_size,
                              hipStream_t stream) {
    const float* x    = (const float*)d_in[0];
    const float* W_ih = (const float*)d_in[1];
    const float* W_hh = (const float*)d_in[2];
    const float* b_ih = (const float*)d_in[3];
    const float* b_hh = (const float*)d_in[4];
    const float* fc_w = (const float*)d_in[5];
    const float* fc_b = (const float*)d_in[6];
    float* out = (float*)d_out;

    const int blocks = B_ / R_;  // 1024
    lstm_fused_kernel<<<blocks, 256, 0, stream>>>(
        x, W_ih, W_hh, b_ih, b_hh, fc_w, fc_b, out);
}

// Round 3
// 243.109 us; speedup vs baseline: 3.6622x; 3.5866x over previous
//
#include <hip/hip_runtime.h>
#include <math.h>

// Problem constants (from reference)
#define B_   4096
#define T_   193
#define D_   50
#define H_   50
#define V_   11
#define BT   16                    // batch rows per block
#define NBLK (B_ / BT)             // 256 blocks
#define XTOT ((size_t)B_ * T_ * D_)

typedef __bf16 bf16x8 __attribute__((ext_vector_type(8)));
typedef float  f32x4  __attribute__((ext_vector_type(4)));

__device__ __forceinline__ float sigf(float v) { return 1.0f / (1.0f + __expf(-v)); }
__device__ __forceinline__ float thf(float v)  { return 2.0f / (1.0f + __expf(-2.0f * v)) - 1.0f; }

// Fused LSTM: per-step GEMM  gates^T[208,16] = Wcat'[208,128] @ act^T[128,16]
//   A (weights, M=gate rows g', K=128):  g' = 4*j + q  (gate-interleaved so the
//     C/D fragment layout row=(lane>>4)*4+reg gives each lane i,f,g,o of ONE
//     hidden unit j in its 4 acc regs -> lane-local cell update)
//   K layout: k in [0,50) = x_t cols; [50,64) pad; [64,114) = h units; 
//             [114,127) pad; k=127 = bias column (B holds constant 1.0)
//   B (activations, K x N=16 batch): x part packed from register-prefetched
//     global loads; h part exchanged through a tiny double-buffered LDS
//     fragment buffer (1 barrier per step).
__global__ __launch_bounds__(256, 1) void lstm_mfma_kernel(
    const float* __restrict__ x,      // [B, T, D]
    const float* __restrict__ W_ih,   // [200, 50]
    const float* __restrict__ W_hh,   // [200, 50]
    const float* __restrict__ b_ih,   // [200]
    const float* __restrict__ b_hh,   // [200]
    const float* __restrict__ fc_w,   // [11, 50]
    const float* __restrict__ fc_b,   // [11]
    float* __restrict__ out)          // [B, 11]
{
    // hb[buf][kstep_half][lane][8 bf16]: B-fragment-ordered h storage.
    // Consumer (kstep s=2,3): lane l reads int4 at hb[buf][s-2][l][0].
    __shared__ __align__(16) unsigned short hb[2][2][64][8];
    __shared__ float hfin[BT * 53];
    __shared__ float lgts[BT][V_];

    const int tid  = threadIdx.x;
    const int wid  = tid >> 6;
    const int lane = tid & 63;
    const int n    = lane & 15;   // batch col within tile / A-frag row m
    const int kg   = lane >> 4;   // k-group (which 8-slice of K) / acc row group
    const int row0 = blockIdx.x * BT;

    const int tbase = (wid == 0) ? 0 : (wid == 1) ? 4 : (wid == 2) ? 7 : 10;
    const int NT    = (wid == 0) ? 4 : 3;

    // ---- init LDS h-fragment buffers: zeros + bias slot (u=63 -> 1.0) ----
    {
        int4 z; z.x = 0; z.y = 0; z.z = 0; z.w = 0;
        reinterpret_cast<int4*>(&hb[0][0][0][0])[tid] = z;   // 256*16B = 4096B
    }
    if (tid < 32) {
        // u=63: sl=1, lc=48|n, ji=7 ; bf16(1.0) = 0x3F80
        hb[tid >> 4][1][48 + (tid & 15)][7] = 0x3F80;
    }

    // ---- load weight A-fragments into registers (constant across t) ----
    // A[m][k]: lane l holds m = 16*tile + (l&15), k = 32*s + (l>>4)*8 + j
    bf16x8 wf[4][4];
    #pragma unroll
    for (int tt = 0; tt < 4; ++tt) {
        #pragma unroll
        for (int s = 0; s < 4; ++s) {
            float tv[8];
            #pragma unroll
            for (int j = 0; j < 8; ++j) tv[j] = 0.0f;
            if (tt < NT) {
                const int gp = 16 * (tbase + tt) + n;  // g'
                const int q  = gp & 3;
                const int ju = gp >> 2;
                if (ju < 50) {
                    const int row = q * 50 + ju;       // original gate row
                    #pragma unroll
                    for (int j = 0; j < 8; ++j) {
                        const int k = s * 32 + kg * 8 + j;
                        float v = 0.0f;
                        if (k < 50)                  v = W_ih[row * 50 + k];
                        else if (k >= 64 && k < 114) v = W_hh[row * 50 + (k - 64)];
                        else if (k == 127)           v = b_ih[row] + b_hh[row];
                        tv[j] = v;
                    }
                }
            }
            bf16x8 w;
            #pragma unroll
            for (int j = 0; j < 8; ++j) w[j] = (__bf16)tv[j];
            wf[tt][s] = w;
        }
    }

    // precomputed LDS write offsets (ushort index within one hb buffer)
    int hoff[4];
    #pragma unroll
    for (int tt = 0; tt < 4; ++tt) {
        const int u = 4 * (tbase + tt) + kg;     // hidden unit this lane owns
        hoff[tt] = (u >> 5) * 512 + ((((u & 31) >> 3) << 4) | n) * 8 + (u & 7);
    }

    __syncthreads();

    // ---- x register prefetch (2 steps deep, float2 = 8B aligned) ----
    auto loadX = [&](float2* xv, int t) {
        const size_t base = ((size_t)(row0 + n) * T_ + t) * D_;
        #pragma unroll
        for (int i = 0; i < 8; ++i) {
            const int c = ((i >> 2) * 32) + kg * 8 + (i & 3) * 2;
            size_t e = base + (size_t)c;
            if (e > XTOT - 2) e = XTOT - 2;     // clamp: garbage * 0-weight = 0
            xv[i] = *reinterpret_cast<const float2*>(x + e);
        }
    };

    float cst[4] = {0.0f, 0.0f, 0.0f, 0.0f};

    auto step = [&](bool last, float2* xv, int tload, int rcur) {
        // pack x B-frags (ksteps 0,1): B[k][n], k = 32s + kg*8 + j
        bf16x8 bx0, bx1;
        #pragma unroll
        for (int i = 0; i < 4; ++i) {
            bx0[2 * i]     = (__bf16)xv[i].x;
            bx0[2 * i + 1] = (__bf16)xv[i].y;
            bx1[2 * i]     = (__bf16)xv[4 + i].x;
            bx1[2 * i + 1] = (__bf16)xv[4 + i].y;
        }
        // h B-frags (ksteps 2,3) from LDS
        const int4* hbv = reinterpret_cast<const int4*>(&hb[rcur][0][0][0]);
        const int4 h0i = hbv[lane];
        const int4 h1i = hbv[64 + lane];
        const bf16x8 bh0 = __builtin_bit_cast(bf16x8, h0i);
        const bf16x8 bh1 = __builtin_bit_cast(bf16x8, h1i);

        f32x4 acc[4];
        #pragma unroll
        for (int tt = 0; tt < 4; ++tt) {
            if (tt < NT) {
                f32x4 a = {0.0f, 0.0f, 0.0f, 0.0f};
                a = __builtin_amdgcn_mfma_f32_16x16x32_bf16(wf[tt][0], bx0, a, 0, 0, 0);
                a = __builtin_amdgcn_mfma_f32_16x16x32_bf16(wf[tt][1], bx1, a, 0, 0, 0);
                a = __builtin_amdgcn_mfma_f32_16x16x32_bf16(wf[tt][2], bh0, a, 0, 0, 0);
                a = __builtin_amdgcn_mfma_f32_16x16x32_bf16(wf[tt][3], bh1, a, 0, 0, 0);
                acc[tt] = a;
            }
        }

        loadX(xv, tload);  // issue next prefetch; latency hides under act phase

        unsigned short* hbw = &hb[rcur ^ 1][0][0][0];
        #pragma unroll
        for (int tt = 0; tt < 4; ++tt) {
            if (tt < NT) {
                const float gi = acc[tt][0];
                const float gf = acc[tt][1];
                const float gg = acc[tt][2];
                const float go = acc[tt][3];
                const float ii = sigf(gi);
                const float ff = sigf(gf);
                const float g2 = thf(gg);
                const float oo = sigf(go);
                cst[tt] = ff * cst[tt] + ii * g2;
                const float h = oo * thf(cst[tt]);
                hbw[hoff[tt]] = __builtin_bit_cast(unsigned short, (__bf16)h);
                if (last) hfin[n * 53 + (4 * (tbase + tt) + kg)] = h;
            }
        }
        __syncthreads();
    };

    float2 xA[8], xB[8];
    loadX(xA, 0);
    loadX(xB, 1);

    int cur = 0;
    for (int t = 0; t < T_ - 1; t += 2) {
        int t2 = t + 2;
        int t3 = (t + 3 < T_) ? (t + 3) : (T_ - 1);
        step(false, xA, t2, cur);
        cur ^= 1;
        step(false, xB, t3, cur);
        cur ^= 1;
    }
    step(true, xA, T_ - 1, cur);   // t = 192; redundant load, harmless

    // ---- FC head + log_softmax (16 x 11 outputs per block) ----
    if (tid < BT * V_) {
        const int bn = tid / V_;
        const int v  = tid % V_;
        float a = fc_b[v];
        #pragma unroll
        for (int j = 0; j < 50; ++j) {
            float hj = hfin[bn * 53 + j];
            hj = hj > 0.0f ? hj : 0.0f;
            a = fmaf(hj, fc_w[v * 50 + j], a);
        }
        lgts[bn][v] = a;
    }
    __syncthreads();
    if (tid < BT * V_) {
        const int bn = tid / V_;
        const int v  = tid % V_;
        float m = -1e30f;
        #pragma unroll
        for (int u = 0; u < V_; ++u) m = fmaxf(m, lgts[bn][u]);
        float s = 0.0f;
        #pragma unroll
        for (int u = 0; u < V_; ++u) s += __expf(lgts[bn][u] - m);
        out[(size_t)(row0 + bn) * V_ + v] = lgts[bn][v] - m - __logf(s);
    }
}

extern "C" void kernel_launch(void* const* d_in, const int* in_sizes, int n_in,
                              void* d_out, int out_size, void* d_ws, size_t ws_size,
                              hipStream_t stream) {
    const float* x    = (const float*)d_in[0];
    const float* W_ih = (const float*)d_in[1];
    const float* W_hh = (const float*)d_in[2];
    const float* b_ih = (const float*)d_in[3];
    const float* b_hh = (const float*)d_in[4];
    const float* fc_w = (const float*)d_in[5];
    const float* fc_b = (const float*)d_in[6];
    float* out = (float*)d_out;

    lstm_mfma_kernel<<<NBLK, 256, 0, stream>>>(
        x, W_ih, W_hh, b_ih, b_hh, fc_w, fc_b, out);
}

// Round 4
// 236.588 us; speedup vs baseline: 3.7632x; 1.0276x over previous
//
#include <hip/hip_runtime.h>
#include <math.h>

// Problem constants
#define B_   4096
#define T_   193
#define D_   50
#define H_   50
#define V_   11
#define BT   16                    // batch rows per block
#define NBLK (B_ / BT)             // 256 blocks
#define CH   64                    // timesteps staged per LDS chunk
#define NCH  4                     // chunks: 64,64,64,1

typedef __bf16 bf16x8 __attribute__((ext_vector_type(8)));
typedef float  f32x4  __attribute__((ext_vector_type(4)));

__device__ __forceinline__ float sigf(float v) { return 1.0f / (1.0f + __expf(-v)); }
__device__ __forceinline__ float thf(float v)  { return 2.0f / (1.0f + __expf(-2.0f * v)) - 1.0f; }

// Per-step GEMM  gates^T[208,16] = Wcat'[208,128] @ act^T[128,16] via
// mfma_f32_16x16x32_bf16, fp32 accum. Gate interleave g' = 4*j + q puts
// {i,f,g,o} of hidden unit j in one lane's 4 acc regs (lane-local cell update).
// K layout: [0,50) x_t; [50,64) pad; [64,114) h; [114,127) pad; 127 = bias
// (B-slot holds constant 1.0).
//
// R4 change vs R3: x is staged per 64-step chunk into LDS (pre-packed bf16
// B-fragment order). The steady-state loop has NO global memory ops, so the
// per-step __syncthreads (which drains vmcnt(0)) no longer exposes HBM
// latency 193x — only 4 staging drains total.
__global__ __launch_bounds__(256, 1) void lstm_mfma_kernel(
    const float* __restrict__ x,      // [B, T, D]
    const float* __restrict__ W_ih,   // [200, 50]
    const float* __restrict__ W_hh,   // [200, 50]
    const float* __restrict__ b_ih,   // [200]
    const float* __restrict__ b_hh,   // [200]
    const float* __restrict__ fc_w,   // [11, 50]
    const float* __restrict__ fc_b,   // [11]
    float* __restrict__ out)          // [B, 11]
{
    // xs: [tc][s][lane][8 bf16] fragment-ordered x chunk. 64*2*64*16B = 128 KB
    __shared__ __align__(16) unsigned short xs[CH * 2 * 64 * 8];
    // hb: double-buffered h B-fragments + bias slot. 4 KB
    __shared__ __align__(16) unsigned short hb[2 * 2 * 64 * 8];
    __shared__ float hfin[BT * 53];
    __shared__ float lgts[BT][V_];

    const int tid  = threadIdx.x;
    const int wid  = tid >> 6;
    const int lane = tid & 63;
    const int n    = lane & 15;   // batch col within tile
    const int kg   = lane >> 4;   // k-group
    const int row0 = blockIdx.x * BT;

    const int tbase = (wid == 0) ? 0 : (wid == 1) ? 4 : (wid == 2) ? 7 : 10;
    const int NT    = (wid == 0) ? 4 : 3;

    // ---- init hb: zeros + bias slot (u=63 -> bf16 1.0) in both buffers ----
    {
        int4 z; z.x = 0; z.y = 0; z.z = 0; z.w = 0;
        reinterpret_cast<int4*>(hb)[tid] = z;   // 256*16B = 4096B
    }
    if (tid < 32) {
        // u=63: sl=1, frag-lane=48|n, j=7 ; bf16(1.0) = 0x3F80
        hb[((tid >> 4) * 2 + 1) * 512 + (48 + (tid & 15)) * 8 + 7] = 0x3F80;
    }

    // ---- weight A-fragments in registers (constant across t) ----
    bf16x8 wf[4][4];
    #pragma unroll
    for (int tt = 0; tt < 4; ++tt) {
        #pragma unroll
        for (int s = 0; s < 4; ++s) {
            float tv[8];
            #pragma unroll
            for (int j = 0; j < 8; ++j) tv[j] = 0.0f;
            if (tt < NT) {
                const int gp = 16 * (tbase + tt) + n;  // g'
                const int q  = gp & 3;
                const int ju = gp >> 2;
                if (ju < 50) {
                    const int row = q * 50 + ju;
                    #pragma unroll
                    for (int j = 0; j < 8; ++j) {
                        const int k = s * 32 + kg * 8 + j;
                        float v = 0.0f;
                        if (k < 50)                  v = W_ih[row * 50 + k];
                        else if (k >= 64 && k < 114) v = W_hh[row * 50 + (k - 64)];
                        else if (k == 127)           v = b_ih[row] + b_hh[row];
                        tv[j] = v;
                    }
                }
            }
            bf16x8 w;
            #pragma unroll
            for (int j = 0; j < 8; ++j) w[j] = (__bf16)tv[j];
            wf[tt][s] = w;
        }
    }

    // LDS write offsets for h (ushort index within one hb buffer)
    int hoff[4];
    #pragma unroll
    for (int tt = 0; tt < 4; ++tt) {
        const int u = 4 * (tbase + tt) + kg;
        hoff[tt] = (u >> 5) * 512 + ((((u & 31) >> 3) << 4) | n) * 8 + (u & 7);
    }

    float cst[4] = {0.0f, 0.0f, 0.0f, 0.0f};
    int cur = 0;

    for (int c = 0; c < NCH; ++c) {
        const int t0 = c * CH;
        const int L  = (T_ - t0 < CH) ? (T_ - t0) : CH;

        // ---- stage chunk: pack x[t0..t0+L) into bf16 B-fragment order ----
        // frag fi = (tc*2 + s)*64 + l ; thread handles fi = tid, tid+256, ...
        const int nfrag = L * 128;
        #pragma unroll 4
        for (int fi = tid; fi < nfrag; fi += 256) {
            const int tc  = fi >> 7;
            const int rem = fi & 127;
            const int s   = rem >> 6;
            const int l   = rem & 63;
            const int nn  = l & 15;
            const int kk  = l >> 4;
            const float* base = x + ((size_t)(row0 + nn) * T_ + (t0 + tc)) * D_;
            float2 v[4];
            #pragma unroll
            for (int j = 0; j < 4; ++j) {
                int col = 32 * s + kk * 8 + 2 * j;
                if (col > 48) col = 48;   // clamp: finite garbage * 0-weight
                v[j] = *reinterpret_cast<const float2*>(base + col);
            }
            bf16x8 w;
            #pragma unroll
            for (int j = 0; j < 4; ++j) {
                w[2 * j]     = (__bf16)v[j].x;
                w[2 * j + 1] = (__bf16)v[j].y;
            }
            reinterpret_cast<int4*>(xs)[fi] = __builtin_bit_cast(int4, w);
        }
        __syncthreads();   // the ONE vmcnt-drain per chunk

        // x fragments for step 0 of this chunk
        const int4* xsv = reinterpret_cast<const int4*>(xs);
        bf16x8 bx0 = __builtin_bit_cast(bf16x8, xsv[lane]);
        bf16x8 bx1 = __builtin_bit_cast(bf16x8, xsv[64 + lane]);

        for (int tc = 0; tc < L; ++tc) {
            const bool last = (t0 + tc == T_ - 1);

            // h fragments (written by all waves last step, visible post-barrier)
            const int4* hbv = reinterpret_cast<const int4*>(hb) + cur * 128;
            const bf16x8 bh0 = __builtin_bit_cast(bf16x8, hbv[lane]);
            const bf16x8 bh1 = __builtin_bit_cast(bf16x8, hbv[64 + lane]);

            // split accumulators: x-chain independent of the h ds_read
            f32x4 acc[4];
            #pragma unroll
            for (int tt = 0; tt < 4; ++tt) {
                if (tt < NT) {
                    f32x4 ax = {0.0f, 0.0f, 0.0f, 0.0f};
                    ax = __builtin_amdgcn_mfma_f32_16x16x32_bf16(wf[tt][0], bx0, ax, 0, 0, 0);
                    ax = __builtin_amdgcn_mfma_f32_16x16x32_bf16(wf[tt][1], bx1, ax, 0, 0, 0);
                    f32x4 ah = {0.0f, 0.0f, 0.0f, 0.0f};
                    ah = __builtin_amdgcn_mfma_f32_16x16x32_bf16(wf[tt][2], bh0, ah, 0, 0, 0);
                    ah = __builtin_amdgcn_mfma_f32_16x16x32_bf16(wf[tt][3], bh1, ah, 0, 0, 0);
                    acc[tt] = ax + ah;
                }
            }

            // prefetch next step's x frags (chunk-stable LDS; clamped at tail)
            const int tn = (tc + 1 < L) ? (tc + 1) : tc;
            const bf16x8 nx0 = __builtin_bit_cast(bf16x8, xsv[tn * 128 + lane]);
            const bf16x8 nx1 = __builtin_bit_cast(bf16x8, xsv[tn * 128 + 64 + lane]);

            // activations + h write  [gate order i,f,g,o in acc regs 0..3]
            unsigned short* hbw = hb + (cur ^ 1) * 1024;
            #pragma unroll
            for (int tt = 0; tt < 4; ++tt) {
                if (tt < NT) {
                    const float ii = sigf(acc[tt][0]);
                    const float ff = sigf(acc[tt][1]);
                    const float g2 = thf(acc[tt][2]);
                    const float oo = sigf(acc[tt][3]);
                    cst[tt] = ff * cst[tt] + ii * g2;
                    const float h = oo * thf(cst[tt]);
                    hbw[hoff[tt]] = __builtin_bit_cast(unsigned short, (__bf16)h);
                    if (last) hfin[n * 53 + (4 * (tbase + tt) + kg)] = h;
                }
            }
            __syncthreads();   // LDS-only drain in steady state
            bx0 = nx0;
            bx1 = nx1;
            cur ^= 1;
        }
    }

    // ---- FC head + log_softmax ----
    if (tid < BT * V_) {
        const int bn = tid / V_;
        const int v  = tid % V_;
        float a = fc_b[v];
        #pragma unroll
        for (int j = 0; j < 50; ++j) {
            float hj = hfin[bn * 53 + j];
            hj = hj > 0.0f ? hj : 0.0f;
            a = fmaf(hj, fc_w[v * 50 + j], a);
        }
        lgts[bn][v] = a;
    }
    __syncthreads();
    if (tid < BT * V_) {
        const int bn = tid / V_;
        const int v  = tid % V_;
        float m = -1e30f;
        #pragma unroll
        for (int u = 0; u < V_; ++u) m = fmaxf(m, lgts[bn][u]);
        float s = 0.0f;
        #pragma unroll
        for (int u = 0; u < V_; ++u) s += __expf(lgts[bn][u] - m);
        out[(size_t)(row0 + bn) * V_ + v] = lgts[bn][v] - m - __logf(s);
    }
}

extern "C" void kernel_launch(void* const* d_in, const int* in_sizes, int n_in,
                              void* d_out, int out_size, void* d_ws, size_t ws_size,
                              hipStream_t stream) {
    const float* x    = (const float*)d_in[0];
    const float* W_ih = (const float*)d_in[1];
    const float* W_hh = (const float*)d_in[2];
    const float* b_ih = (const float*)d_in[3];
    const float* b_hh = (const float*)d_in[4];
    const float* fc_w = (const float*)d_in[5];
    const float* fc_b = (const float*)d_in[6];
    float* out = (float*)d_out;

    lstm_mfma_kernel<<<NBLK, 256, 0, stream>>>(
        x, W_ih, W_hh, b_ih, b_hh, fc_w, fc_b, out);
}